// Round 1
// baseline (2602.827 us; speedup 1.0000x reference)
//
#include <hip/hip_runtime.h>
#include <hip/hip_bf16.h>

typedef __attribute__((ext_vector_type(8))) short short8;
typedef __attribute__((ext_vector_type(4))) float f32x4;

#define DIM    1024
#define NHEADS 16
#define HDIM   64
#define SEQ    2048
#define BATCH  4
#define ROWS   (BATCH * SEQ)   // 8192
#define QKV_N  (3 * DIM)       // 3072

__device__ __forceinline__ unsigned short f2bf(float f) {
    union { float f; unsigned u; } v; v.f = f;
    unsigned u = v.u;
    return (unsigned short)((u + 0x7fffu + ((u >> 16) & 1u)) >> 16);   // RNE
}
__device__ __forceinline__ float bf2f(unsigned short h) {
    union { unsigned u; float f; } v; v.u = ((unsigned)h) << 16;
    return v.f;
}

// ---------------------------------------------------------------------------
// bf16 MFMA GEMM: C[M,N] = A[M,K] @ W[K,N] (+bias). A is fp32 or bf16(ws),
// W fp32 (converted on stage). 64x64 tile, BK=32, 256 threads = 4 waves,
// each wave does a 32x32 quadrant (2x2 fragments of 16x16x32).
// ---------------------------------------------------------------------------
template<bool A_BF16, bool WITH_BIAS>
__global__ __launch_bounds__(256)
void gemm_kernel(const void* __restrict__ Ap, const float* __restrict__ W,
                 const float* __restrict__ bias, void* __restrict__ Cp,
                 int M, int N, int K)
{
    // pad rows to 48 ushorts (96B, 16B-aligned) to soften bank conflicts
    __shared__ alignas(16) unsigned short LA[64][48];   // [m][k]
    __shared__ alignas(16) unsigned short LBT[64][48];  // [n][k]

    const int tid  = threadIdx.x;
    const int lane = tid & 63;
    const int w    = tid >> 6;
    const int wr   = w >> 1, wc = w & 1;
    const int bm   = blockIdx.y * 64;
    const int bn   = blockIdx.x * 64;

    f32x4 acc[2][2] = {};

    const int a_row = tid >> 2;          // 0..63
    const int a_col = (tid & 3) * 8;     // 0,8,16,24
    const int b_k   = tid >> 3;          // 0..31
    const int b_n   = (tid & 7) * 8;     // 0..56

    for (int k0 = 0; k0 < K; k0 += 32) {
        if (A_BF16) {
            const unsigned short* src =
                (const unsigned short*)Ap + (size_t)(bm + a_row) * K + k0 + a_col;
            #pragma unroll
            for (int i = 0; i < 8; ++i) LA[a_row][a_col + i] = src[i];
        } else {
            const float* src = (const float*)Ap + (size_t)(bm + a_row) * K + k0 + a_col;
            #pragma unroll
            for (int i = 0; i < 8; ++i) LA[a_row][a_col + i] = f2bf(src[i]);
        }
        {
            const float* src = W + (size_t)(k0 + b_k) * N + bn + b_n;
            #pragma unroll
            for (int i = 0; i < 8; ++i) LBT[b_n + i][b_k] = f2bf(src[i]);
        }
        __syncthreads();

        const int kq = (lane >> 4) * 8;   // k sub-chunk: 0,8,16,24
        const int r  = lane & 15;
        short8 af[2], bfr[2];
        #pragma unroll
        for (int mi = 0; mi < 2; ++mi)
            af[mi] = *(const short8*)&LA[wr * 32 + mi * 16 + r][kq];
        #pragma unroll
        for (int ni = 0; ni < 2; ++ni)
            bfr[ni] = *(const short8*)&LBT[wc * 32 + ni * 16 + r][kq];
        #pragma unroll
        for (int mi = 0; mi < 2; ++mi)
            #pragma unroll
            for (int ni = 0; ni < 2; ++ni)
                acc[mi][ni] = __builtin_amdgcn_mfma_f32_16x16x32_bf16(
                    af[mi], bfr[ni], acc[mi][ni], 0, 0, 0);
        __syncthreads();
    }

    // C/D layout (verified, m89/m91): col = lane&15, row = (lane>>4)*4 + j
    const int col_l = lane & 15;
    const int row_l = (lane >> 4) * 4;
    #pragma unroll
    for (int mi = 0; mi < 2; ++mi)
        #pragma unroll
        for (int ni = 0; ni < 2; ++ni) {
            const int gcol = bn + wc * 32 + ni * 16 + col_l;
            #pragma unroll
            for (int j = 0; j < 4; ++j) {
                const int grow = bm + wr * 32 + mi * 16 + row_l + j;
                const float v = acc[mi][ni][j];
                if (WITH_BIAS)
                    ((float*)Cp)[(size_t)grow * N + gcol] = v + bias[gcol];
                else
                    ((unsigned short*)Cp)[(size_t)grow * N + gcol] = f2bf(v);
            }
        }
}

// ---------------------------------------------------------------------------
// Flash-style attention, fp32 math, bf16 K/V in LDS.
// Block: 256 threads, 32 queries of one (b,h); key tiles of 128.
// Thread t: q = t>>3, owns dims d0 = (t&7)*8 .. +7 of the output.
// ---------------------------------------------------------------------------
__global__ __launch_bounds__(256)
void attn_kernel(const unsigned short* __restrict__ qkv,
                 unsigned short* __restrict__ att)
{
    __shared__ float          Qs[32][68];     // +4 pad: conflict-free QK reads
    __shared__ unsigned short Ks[128][66];    // +2 pad: odd bank stride
    __shared__ unsigned short Vs[128][66];
    __shared__ float          S[32][132];     // +4 pad
    __shared__ float mrow[32], lrow[32], frow[32];

    const int tid = threadIdx.x;
    const int b   = blockIdx.z, h = blockIdx.y;
    const int q0  = blockIdx.x * 32;
    const size_t base = (size_t)b * SEQ * QKV_N;

    {   // load Q (scale folded in)
        const int q = tid >> 3, d = (tid & 7) * 8;
        const unsigned short* src =
            qkv + base + (size_t)(q0 + q) * QKV_N + h * HDIM + d;
        #pragma unroll
        for (int i = 0; i < 8; ++i) Qs[q][d + i] = bf2f(src[i]) * 0.125f;
    }
    if (tid < 32) { mrow[tid] = -1e30f; lrow[tid] = 0.f; }

    const int q  = tid >> 3;
    const int d0 = (tid & 7) * 8;
    const int jl = tid & 7;
    float o[8] = {};

    for (int kt = 0; kt < SEQ; kt += 128) {
        __syncthreads();   // Q ready (iter0) / prev PV done with Ks,Vs,S
        {   // stage K,V tile (bf16)
            const int j = tid >> 1, dd = (tid & 1) * 32;
            const unsigned short* ksrc =
                qkv + base + (size_t)(kt + j) * QKV_N + DIM + h * HDIM + dd;
            const unsigned short* vsrc = ksrc + DIM;
            #pragma unroll
            for (int i = 0; i < 32; ++i) { Ks[j][dd + i] = ksrc[i]; Vs[j][dd + i] = vsrc[i]; }
        }
        __syncthreads();
        {   // S[q][j] = Qs[q] . K[j]   (16 dots per thread)
            #pragma unroll 4
            for (int jj = 0; jj < 16; ++jj) {
                const int j = jj * 8 + jl;
                float s = 0.f;
                #pragma unroll
                for (int d = 0; d < 64; ++d) s += Qs[q][d] * bf2f(Ks[j][d]);
                S[q][j] = s;
            }
        }
        __syncthreads();
        if (tid < 32) {   // online softmax row update (serial per row; baseline)
            float m = mrow[tid], nm = m;
            for (int j = 0; j < 128; ++j) nm = fmaxf(nm, S[tid][j]);
            const float f = __expf(m - nm);
            float sum = 0.f;
            for (int j = 0; j < 128; ++j) {
                const float p = __expf(S[tid][j] - nm);
                S[tid][j] = p; sum += p;
            }
            lrow[tid] = lrow[tid] * f + sum;
            mrow[tid] = nm;
            frow[tid] = f;
        }
        __syncthreads();
        {   // PV accumulate
            const float f = frow[q];
            #pragma unroll
            for (int c = 0; c < 8; ++c) o[c] *= f;
            for (int j = 0; j < 128; ++j) {
                const float p = S[q][j];
                #pragma unroll
                for (int c = 0; c < 8; ++c) o[c] += p * bf2f(Vs[j][d0 + c]);
            }
        }
    }

    {   // write attended / l  as bf16 into ws2 [row][h*64+d]
        const float inv = 1.f / lrow[q];
        unsigned short* dst = att + (size_t)(b * SEQ + q0 + q) * DIM + h * HDIM + d0;
        #pragma unroll
        for (int c = 0; c < 8; ++c) dst[c] = f2bf(o[c] * inv);
    }
}

// ---------------------------------------------------------------------------
extern "C" void kernel_launch(void* const* d_in, const int* in_sizes, int n_in,
                              void* d_out, int out_size, void* d_ws, size_t ws_size,
                              hipStream_t stream)
{
    const float* x     = (const float*)d_in[0];
    const float* w_qkv = (const float*)d_in[1];
    const float* w_out = (const float*)d_in[2];
    const float* b_out = (const float*)d_in[3];
    float* out = (float*)d_out;

    unsigned short* qkv = (unsigned short*)d_ws;                       // [8192][3072] bf16
    unsigned short* att = qkv + (size_t)ROWS * QKV_N;                  // [8192][1024] bf16

    // 1) qkv = x @ w_qkv  -> bf16 ws
    gemm_kernel<false, false><<<dim3(QKV_N / 64, ROWS / 64), 256, 0, stream>>>(
        x, w_qkv, nullptr, qkv, ROWS, QKV_N, DIM);

    // 2) attention -> att (bf16 ws)
    attn_kernel<<<dim3(SEQ / 32, NHEADS, BATCH), 256, 0, stream>>>(qkv, att);

    // 3) out = att @ w_out + b_out  -> fp32 d_out
    gemm_kernel<true, true><<<dim3(DIM / 64, ROWS / 64), 256, 0, stream>>>(
        att, w_out, b_out, out, ROWS, DIM, DIM);
}

// Round 2
// 577.041 us; speedup vs baseline: 4.5106x; 4.5106x over previous
//
#include <hip/hip_runtime.h>
#include <hip/hip_bf16.h>

typedef __attribute__((ext_vector_type(8))) short short8;
typedef __attribute__((ext_vector_type(4))) float f32x4;

#define DIM    1024
#define NHEADS 16
#define HDIM   64
#define SEQ    2048
#define BATCH  4
#define ROWS   (BATCH * SEQ)   // 8192
#define QKV_N  (3 * DIM)       // 3072

__device__ __forceinline__ unsigned short f2bf(float f) {
    union { float f; unsigned u; } v; v.f = f;
    unsigned u = v.u;
    return (unsigned short)((u + 0x7fffu + ((u >> 16) & 1u)) >> 16);   // RNE
}
__device__ __forceinline__ float bf2f(unsigned short h) {
    union { unsigned u; float f; } v; v.u = ((unsigned)h) << 16;
    return v.f;
}

// ---------------------------------------------------------------------------
// bf16 MFMA GEMM: C[M,N] = A[M,K] @ W[K,N] (+bias). 64x64 tile, BK=32,
// 256 threads = 4 waves, each wave a 32x32 quadrant (2x2 16x16x32 frags).
// ---------------------------------------------------------------------------
template<bool A_BF16, bool WITH_BIAS>
__global__ __launch_bounds__(256)
void gemm_kernel(const void* __restrict__ Ap, const float* __restrict__ W,
                 const float* __restrict__ bias, void* __restrict__ Cp,
                 int M, int N, int K)
{
    __shared__ alignas(16) unsigned short LA[64][48];   // [m][k]
    __shared__ alignas(16) unsigned short LBT[64][48];  // [n][k]

    const int tid  = threadIdx.x;
    const int lane = tid & 63;
    const int w    = tid >> 6;
    const int wr   = w >> 1, wc = w & 1;
    const int bm   = blockIdx.y * 64;
    const int bn   = blockIdx.x * 64;

    f32x4 acc[2][2] = {};

    const int a_row = tid >> 2;          // 0..63
    const int a_col = (tid & 3) * 8;     // 0,8,16,24
    const int b_k   = tid >> 3;          // 0..31
    const int b_n   = (tid & 7) * 8;     // 0..56

    for (int k0 = 0; k0 < K; k0 += 32) {
        if (A_BF16) {
            const unsigned short* src =
                (const unsigned short*)Ap + (size_t)(bm + a_row) * K + k0 + a_col;
            #pragma unroll
            for (int i = 0; i < 8; ++i) LA[a_row][a_col + i] = src[i];
        } else {
            const float* src = (const float*)Ap + (size_t)(bm + a_row) * K + k0 + a_col;
            #pragma unroll
            for (int i = 0; i < 8; ++i) LA[a_row][a_col + i] = f2bf(src[i]);
        }
        {
            const float* src = W + (size_t)(k0 + b_k) * N + bn + b_n;
            #pragma unroll
            for (int i = 0; i < 8; ++i) LBT[b_n + i][b_k] = f2bf(src[i]);
        }
        __syncthreads();

        const int kq = (lane >> 4) * 8;
        const int r  = lane & 15;
        short8 af[2], bfr[2];
        #pragma unroll
        for (int mi = 0; mi < 2; ++mi)
            af[mi] = *(const short8*)&LA[wr * 32 + mi * 16 + r][kq];
        #pragma unroll
        for (int ni = 0; ni < 2; ++ni)
            bfr[ni] = *(const short8*)&LBT[wc * 32 + ni * 16 + r][kq];
        #pragma unroll
        for (int mi = 0; mi < 2; ++mi)
            #pragma unroll
            for (int ni = 0; ni < 2; ++ni)
                acc[mi][ni] = __builtin_amdgcn_mfma_f32_16x16x32_bf16(
                    af[mi], bfr[ni], acc[mi][ni], 0, 0, 0);
        __syncthreads();
    }

    const int col_l = lane & 15;
    const int row_l = (lane >> 4) * 4;
    #pragma unroll
    for (int mi = 0; mi < 2; ++mi)
        #pragma unroll
        for (int ni = 0; ni < 2; ++ni) {
            const int gcol = bn + wc * 32 + ni * 16 + col_l;
            #pragma unroll
            for (int j = 0; j < 4; ++j) {
                const int grow = bm + wr * 32 + mi * 16 + row_l + j;
                const float v = acc[mi][ni][j];
                if (WITH_BIAS)
                    ((float*)Cp)[(size_t)grow * N + gcol] = v + bias[gcol];
                else
                    ((unsigned short*)Cp)[(size_t)grow * N + gcol] = f2bf(v);
            }
        }
}

// ---------------------------------------------------------------------------
// MFMA flash attention. Block = 256 thr (4 waves) = 64 q-rows of one (b,h).
// Wave w owns q rows [w*16, w*16+16). K-tiles of 64 keys.
// QK^T and PV via mfma_f32_16x16x32_bf16; online softmax in registers with
// 16-lane shfl_xor reductions (fragment C/D layout: col=lane&15,
// row=(lane>>4)*4+jr  [verified m89/m91]).
// ---------------------------------------------------------------------------
__global__ __launch_bounds__(256)
void attn_kernel(const unsigned short* __restrict__ qkv,
                 unsigned short* __restrict__ att)
{
    // stride 72 elems (144B): wave b128 reads spread evenly over all 32 banks
    __shared__ alignas(16) unsigned short Ks[64][72];   // [key][d]
    __shared__ alignas(16) unsigned short Vt[64][72];   // [d][key]
    __shared__ alignas(16) unsigned short Ps[64][72];   // wave w rows [w*16,+16): [qrow][key]

    const int tid  = threadIdx.x;
    const int lane = tid & 63;
    const int w    = tid >> 6;
    const int b  = blockIdx.z, h = blockIdx.y;
    const int q0 = blockIdx.x * 64;
    const size_t base = (size_t)b * SEQ * QKV_N + (size_t)h * HDIM;

    const int r16 = lane & 15;      // fragment row/col index
    const int g   = lane >> 4;      // k-group (8 elems each)

    // Q fragments (A operand): row q0+w*16+r16, k = g*8+j (+32 for qf[1])
    short8 qf[2];
    {
        const unsigned short* qrow = qkv + base + (size_t)(q0 + w * 16 + r16) * QKV_N;
        qf[0] = *(const short8*)(qrow + g * 8);
        qf[1] = *(const short8*)(qrow + 32 + g * 8);
    }

    f32x4 oacc[4] = {};             // dt: col d = dt*16+r16, rows g*4+jr
    float m_r[4], l_r[4];
    #pragma unroll
    for (int i = 0; i < 4; ++i) { m_r[i] = -3e38f; l_r[i] = 0.f; }

    const int sj = tid >> 2;            // staging: key row 0..63
    const int sd = (tid & 3) * 16;      // d chunk

    for (int kt = 0; kt < SEQ; kt += 64) {
        __syncthreads();    // prev iter done reading Ks/Vt
        {   // stage K (row-major) and V (transposed)
            const unsigned short* ksrc = qkv + base + (size_t)(kt + sj) * QKV_N + DIM + sd;
            const unsigned short* vsrc = ksrc + DIM;
            *(short8*)&Ks[sj][sd]     = *(const short8*)(ksrc);
            *(short8*)&Ks[sj][sd + 8] = *(const short8*)(ksrc + 8);
            short8 v0 = *(const short8*)(vsrc);
            short8 v1 = *(const short8*)(vsrc + 8);
            #pragma unroll
            for (int i = 0; i < 8; ++i) {
                Vt[sd + i][sj]     = v0[i];
                Vt[sd + 8 + i][sj] = v1[i];
            }
        }
        __syncthreads();

        // S = Q K^T : 4 key-tiles of 16
        f32x4 sacc[4] = {};
        #pragma unroll
        for (int jt = 0; jt < 4; ++jt) {
            short8 kf0 = *(const short8*)&Ks[jt * 16 + r16][g * 8];
            short8 kf1 = *(const short8*)&Ks[jt * 16 + r16][32 + g * 8];
            sacc[jt] = __builtin_amdgcn_mfma_f32_16x16x32_bf16(qf[0], kf0, sacc[jt], 0, 0, 0);
            sacc[jt] = __builtin_amdgcn_mfma_f32_16x16x32_bf16(qf[1], kf1, sacc[jt], 0, 0, 0);
        }

        // online softmax (scale 1/8 folded in); all 64 lanes active
        float fscale[4], psum[4];
        #pragma unroll
        for (int jr = 0; jr < 4; ++jr) {
            float tm = fmaxf(fmaxf(sacc[0][jr], sacc[1][jr]),
                             fmaxf(sacc[2][jr], sacc[3][jr]));
            tm = fmaxf(tm, __shfl_xor(tm, 1));
            tm = fmaxf(tm, __shfl_xor(tm, 2));
            tm = fmaxf(tm, __shfl_xor(tm, 4));
            tm = fmaxf(tm, __shfl_xor(tm, 8));
            tm *= 0.125f;
            const float nm = fmaxf(m_r[jr], tm);
            const float f  = __expf(m_r[jr] - nm);
            m_r[jr] = nm;
            fscale[jr] = f;
            float ts = 0.f;
            #pragma unroll
            for (int jt = 0; jt < 4; ++jt) {
                float p = __expf(sacc[jt][jr] * 0.125f - nm);
                // quantize P to bf16 NOW so l matches the PV MFMA inputs
                unsigned short pb = f2bf(p);
                Ps[w * 16 + g * 4 + jr][jt * 16 + r16] = pb;
                ts += bf2f(pb);
            }
            psum[jr] = ts;
        }
        #pragma unroll
        for (int jr = 0; jr < 4; ++jr) {
            float ts = psum[jr];
            ts += __shfl_xor(ts, 1);
            ts += __shfl_xor(ts, 2);
            ts += __shfl_xor(ts, 4);
            ts += __shfl_xor(ts, 8);
            l_r[jr] = l_r[jr] * fscale[jr] + ts;
        }
        #pragma unroll
        for (int dt = 0; dt < 4; ++dt)
            #pragma unroll
            for (int jr = 0; jr < 4; ++jr)
                oacc[dt][jr] *= fscale[jr];

        __syncthreads();    // P visible (wave-local; barrier also orders lgkm)

        // PV: A = P[row=r16][k=key], B = Vt (B[k=key][col=d] = Vt[d][key])
        short8 pf0 = *(const short8*)&Ps[w * 16 + r16][g * 8];
        short8 pf1 = *(const short8*)&Ps[w * 16 + r16][32 + g * 8];
        #pragma unroll
        for (int dt = 0; dt < 4; ++dt) {
            short8 vf0 = *(const short8*)&Vt[dt * 16 + r16][g * 8];
            short8 vf1 = *(const short8*)&Vt[dt * 16 + r16][32 + g * 8];
            oacc[dt] = __builtin_amdgcn_mfma_f32_16x16x32_bf16(pf0, vf0, oacc[dt], 0, 0, 0);
            oacc[dt] = __builtin_amdgcn_mfma_f32_16x16x32_bf16(pf1, vf1, oacc[dt], 0, 0, 0);
        }
    }

    // epilogue: O / l -> att (bf16)
    #pragma unroll
    for (int jr = 0; jr < 4; ++jr) {
        const float inv = 1.f / l_r[jr];
        const int row = q0 + w * 16 + g * 4 + jr;
        unsigned short* dst = att + (size_t)(b * SEQ + row) * DIM + h * HDIM;
        #pragma unroll
        for (int dt = 0; dt < 4; ++dt)
            dst[dt * 16 + r16] = f2bf(oacc[dt][jr] * inv);
    }
}

// ---------------------------------------------------------------------------
extern "C" void kernel_launch(void* const* d_in, const int* in_sizes, int n_in,
                              void* d_out, int out_size, void* d_ws, size_t ws_size,
                              hipStream_t stream)
{
    const float* x     = (const float*)d_in[0];
    const float* w_qkv = (const float*)d_in[1];
    const float* w_out = (const float*)d_in[2];
    const float* b_out = (const float*)d_in[3];
    float* out = (float*)d_out;

    unsigned short* qkv = (unsigned short*)d_ws;                       // [8192][3072] bf16
    unsigned short* att = qkv + (size_t)ROWS * QKV_N;                  // [8192][1024] bf16

    gemm_kernel<false, false><<<dim3(QKV_N / 64, ROWS / 64), 256, 0, stream>>>(
        x, w_qkv, nullptr, qkv, ROWS, QKV_N, DIM);

    attn_kernel<<<dim3(SEQ / 64, NHEADS, BATCH), 256, 0, stream>>>(qkv, att);

    gemm_kernel<true, true><<<dim3(DIM / 64, ROWS / 64), 256, 0, stream>>>(
        att, w_out, b_out, out, ROWS, DIM, DIM);
}

// Round 3
// 382.145 us; speedup vs baseline: 6.8111x; 1.5100x over previous
//
#include <hip/hip_runtime.h>
#include <hip/hip_bf16.h>

typedef __attribute__((ext_vector_type(8))) short short8;
typedef __attribute__((ext_vector_type(4))) short short4v;
typedef __attribute__((ext_vector_type(4))) float f32x4;

#define DIM    1024
#define NHEADS 16
#define HDIM   64
#define SEQ    2048
#define BATCH  4
#define ROWS   8192            // BATCH*SEQ
#define QKV_N  3072            // 3*DIM

__device__ __forceinline__ unsigned short f2bf(float f) {
    union { float f; unsigned u; } v; v.f = f;
    unsigned u = v.u;
    return (unsigned short)((u + 0x7fffu + ((u >> 16) & 1u)) >> 16);   // RNE
}
__device__ __forceinline__ float bf2f(unsigned short h) {
    union { unsigned u; float f; } v; v.u = ((unsigned)h) << 16;
    return v.f;
}

// async global->LDS, 16B per lane; LDS dest = wave-uniform base + lane*16
__device__ __forceinline__ void gload16(const void* g, void* l) {
    __builtin_amdgcn_global_load_lds(
        (const __attribute__((address_space(1))) unsigned int*)g,
        (__attribute__((address_space(3))) unsigned int*)l, 16, 0, 0);
}

// ---------------------------------------------------------------------------
// convert fp32 -> bf16 (flat)
// ---------------------------------------------------------------------------
__global__ __launch_bounds__(256)
void conv_kernel(const float* __restrict__ src, unsigned short* __restrict__ dst, int n4)
{
    const int i = blockIdx.x * 256 + threadIdx.x;
    if (i >= n4) return;
    const float4 v = ((const float4*)src)[i];
    short4v o;
    o[0] = (short)f2bf(v.x); o[1] = (short)f2bf(v.y);
    o[2] = (short)f2bf(v.z); o[3] = (short)f2bf(v.w);
    ((short4v*)dst)[i] = o;
}

// ---------------------------------------------------------------------------
// transpose + convert: src [R][C] fp32 -> dst [C][R] bf16
// ---------------------------------------------------------------------------
__global__ __launch_bounds__(256)
void convT_kernel(const float* __restrict__ src, unsigned short* __restrict__ dst,
                  int R, int C)
{
    __shared__ float T[32][33];
    const int r0 = blockIdx.y * 32, c0 = blockIdx.x * 32;
    const int tc = threadIdx.x & 31, tr = threadIdx.x >> 5;   // 32 x 8
    #pragma unroll
    for (int i = 0; i < 4; ++i)
        T[tr + i * 8][tc] = src[(size_t)(r0 + tr + i * 8) * C + c0 + tc];
    __syncthreads();
    #pragma unroll
    for (int i = 0; i < 4; ++i)
        dst[(size_t)(c0 + tr + i * 8) * R + r0 + tc] = f2bf(T[tc][tr + i * 8]);
}

// ---------------------------------------------------------------------------
// bf16 MFMA GEMM (m97 structure): C[M,N] = A[M,K] @ BT[N,K]^T (+bias).
// 128x128 tile, BK=32, 256 thr = 4 waves (2x2), 4x4 16x16x32 frags per wave.
// Staging via global_load_lds w16 into linear LDS (conflict-free reads:
// row stride 64B -> 64-lane b128 pattern tiles 1024B exactly).
// ---------------------------------------------------------------------------
template<bool WITH_BIAS>
__global__ __launch_bounds__(256)
void gemm_kernel(const unsigned short* __restrict__ A,   // [M][K] bf16
                 const unsigned short* __restrict__ BT,  // [N][K] bf16
                 const float* __restrict__ bias,
                 void* __restrict__ Cp, int M, int N, int K)
{
    __shared__ alignas(16) unsigned short LA[128][32];
    __shared__ alignas(16) unsigned short LB[128][32];

    const int tid  = threadIdx.x;
    const int lane = tid & 63;
    const int w    = tid >> 6;
    const int wr   = w >> 1, wc = w & 1;
    const int bm   = blockIdx.y * 128, bn = blockIdx.x * 128;
    const int r16  = lane & 15, g = lane >> 4;

    f32x4 acc[4][4] = {};

    // staging: chunk = 1KB = 16 rows x 32k; lane l -> row +(l>>2), kgrp (l&3)*8
    const int srow = lane >> 2, skg = (lane & 3) * 8;

    for (int k0 = 0; k0 < K; k0 += 32) {
        #pragma unroll
        for (int c = 0; c < 2; ++c) {
            const int chunk = w * 2 + c;            // 8 chunks over 4 waves
            gload16(A  + (size_t)(bm + chunk * 16 + srow) * K + k0 + skg, &LA[chunk * 16][0]);
            gload16(BT + (size_t)(bn + chunk * 16 + srow) * K + k0 + skg, &LB[chunk * 16][0]);
        }
        __syncthreads();
        short8 af[4], bf_[4];
        #pragma unroll
        for (int i = 0; i < 4; ++i) {
            af[i]  = *(const short8*)&LA[wr * 64 + i * 16 + r16][g * 8];
            bf_[i] = *(const short8*)&LB[wc * 64 + i * 16 + r16][g * 8];
        }
        #pragma unroll
        for (int mi = 0; mi < 4; ++mi)
            #pragma unroll
            for (int ni = 0; ni < 4; ++ni)
                acc[mi][ni] = __builtin_amdgcn_mfma_f32_16x16x32_bf16(
                    af[mi], bf_[ni], acc[mi][ni], 0, 0, 0);
        __syncthreads();
    }

    // C/D layout: col = lane&15, row = (lane>>4)*4 + j  [verified m89/m91]
    #pragma unroll
    for (int mi = 0; mi < 4; ++mi)
        #pragma unroll
        for (int ni = 0; ni < 4; ++ni) {
            const int gcol = bn + wc * 64 + ni * 16 + r16;
            #pragma unroll
            for (int j = 0; j < 4; ++j) {
                const int grow = bm + wr * 64 + mi * 16 + g * 4 + j;
                const float v = acc[mi][ni][j];
                if (WITH_BIAS)
                    ((float*)Cp)[(size_t)grow * N + gcol] = v + bias[gcol];
                else
                    ((unsigned short*)Cp)[(size_t)grow * N + gcol] = f2bf(v);
            }
        }
}

// ---------------------------------------------------------------------------
// MFMA flash attention. Block = 256 thr (4 waves) = 128 q-rows of one (b,h).
// Wave w: q rows [w*32, w*32+32) as 2 16-row fragments. K-tiles of 64 keys.
// K: global_load_lds into linear [64][64] with pre-swizzled source
//    (stored group Gs holds logical group Gs ^ (row&7)) -> conflict-free reads.
// V: lane l = key l; transposed write hits bank l/2 -> conflict-free.
// Ps: XOR-swizzled cols (^ g<<3) -> conflict-free write+read.
// ---------------------------------------------------------------------------
__global__ __launch_bounds__(256)
void attn_kernel(const unsigned short* __restrict__ qkv,
                 unsigned short* __restrict__ att)
{
    __shared__ alignas(16) unsigned short Ks[64][64];   // linear (gload_lds dest)
    __shared__ alignas(16) unsigned short Vt[64][72];   // [d][key]
    __shared__ alignas(16) unsigned short Ps[128][72];  // [qrow][key swizzled]

    const int tid  = threadIdx.x;
    const int lane = tid & 63;
    const int w    = tid >> 6;
    const int b  = blockIdx.z, h = blockIdx.y;
    const int q0 = blockIdx.x * 128;
    const size_t base = (size_t)b * SEQ * QKV_N + (size_t)h * HDIM;

    const int r16 = lane & 15;
    const int g   = lane >> 4;

    // Q fragments: A[row=r16][k=g*8+j]
    short8 qf[2][2];
    #pragma unroll
    for (int mi = 0; mi < 2; ++mi) {
        const unsigned short* qrow =
            qkv + base + (size_t)(q0 + w * 32 + mi * 16 + r16) * QKV_N;
        qf[mi][0] = *(const short8*)(qrow + g * 8);
        qf[mi][1] = *(const short8*)(qrow + 32 + g * 8);
    }

    f32x4 oacc[2][4] = {};
    float m_r[2][4], l_r[2][4];
    #pragma unroll
    for (int mi = 0; mi < 2; ++mi)
        #pragma unroll
        for (int jr = 0; jr < 4; ++jr) { m_r[mi][jr] = -3e38f; l_r[mi][jr] = 0.f; }

    // K staging geometry: chunk c: keys c*8..c*8+7; lane: key +(l>>3), Gs=l&7
    const int krow = lane >> 3;
    const int kGsrc = (lane & 7) ^ (krow & 7);      // pre-swizzled source group

    for (int kt = 0; kt < SEQ; kt += 64) {
        __syncthreads();   // prev tile fully consumed
        // --- stage K via gload_lds (coalesced: 8 lanes cover a 128B row permuted)
        #pragma unroll
        for (int c = 0; c < 2; ++c) {
            const int chunk = w * 2 + c;
            const unsigned short* gsrc =
                qkv + base + (size_t)(kt + chunk * 8 + krow) * QKV_N + DIM + kGsrc * 8;
            gload16(gsrc, &Ks[chunk * 8][0]);
        }
        // --- stage V transposed: wave w covers d [w*16,+16), lane = key
        {
            const unsigned short* vsrc =
                qkv + base + (size_t)(kt + lane) * QKV_N + 2 * DIM + w * 16;
            short8 v0 = *(const short8*)(vsrc);
            short8 v1 = *(const short8*)(vsrc + 8);
            #pragma unroll
            for (int i = 0; i < 8; ++i) {
                Vt[w * 16 + i][lane]     = (unsigned short)v0[i];
                Vt[w * 16 + 8 + i][lane] = (unsigned short)v1[i];
            }
        }
        __syncthreads();

        // --- S = Q K^T
        f32x4 sacc[2][4] = {};
        #pragma unroll
        for (int jt = 0; jt < 4; ++jt) {
            const int row = jt * 16 + r16;
            const int f7  = r16 & 7;
            short8 kf0 = *(const short8*)&Ks[row][(g ^ f7) * 8];
            short8 kf1 = *(const short8*)&Ks[row][((4 + g) ^ f7) * 8];
            sacc[0][jt] = __builtin_amdgcn_mfma_f32_16x16x32_bf16(qf[0][0], kf0, sacc[0][jt], 0, 0, 0);
            sacc[0][jt] = __builtin_amdgcn_mfma_f32_16x16x32_bf16(qf[0][1], kf1, sacc[0][jt], 0, 0, 0);
            sacc[1][jt] = __builtin_amdgcn_mfma_f32_16x16x32_bf16(qf[1][0], kf0, sacc[1][jt], 0, 0, 0);
            sacc[1][jt] = __builtin_amdgcn_mfma_f32_16x16x32_bf16(qf[1][1], kf1, sacc[1][jt], 0, 0, 0);
        }

        // --- online softmax (all 64 lanes active); Ps write XOR-swizzled
        #pragma unroll
        for (int mi = 0; mi < 2; ++mi) {
            float fs[4];
            #pragma unroll
            for (int jr = 0; jr < 4; ++jr) {
                float tm = fmaxf(fmaxf(sacc[mi][0][jr], sacc[mi][1][jr]),
                                 fmaxf(sacc[mi][2][jr], sacc[mi][3][jr]));
                tm = fmaxf(tm, __shfl_xor(tm, 1));
                tm = fmaxf(tm, __shfl_xor(tm, 2));
                tm = fmaxf(tm, __shfl_xor(tm, 4));
                tm = fmaxf(tm, __shfl_xor(tm, 8));
                tm *= 0.125f;
                const float nm = fmaxf(m_r[mi][jr], tm);
                const float f  = __expf(m_r[mi][jr] - nm);
                m_r[mi][jr] = nm;
                fs[jr] = f;
                const int prow = w * 32 + mi * 16 + g * 4 + jr;
                float ts = 0.f;
                #pragma unroll
                for (int jt = 0; jt < 4; ++jt) {
                    const float p = __expf(sacc[mi][jt][jr] * 0.125f - nm);
                    const unsigned short pb = f2bf(p);
                    Ps[prow][(jt * 16 + r16) ^ (g << 3)] = pb;
                    ts += bf2f(pb);
                }
                ts += __shfl_xor(ts, 1);
                ts += __shfl_xor(ts, 2);
                ts += __shfl_xor(ts, 4);
                ts += __shfl_xor(ts, 8);
                l_r[mi][jr] = l_r[mi][jr] * f + ts;
            }
            #pragma unroll
            for (int dt = 0; dt < 4; ++dt)
                #pragma unroll
                for (int jr = 0; jr < 4; ++jr)
                    oacc[mi][dt][jr] *= fs[jr];
        }
        __syncthreads();   // Ps visible

        // --- PV: A = P (swizzle-read), B = V^T from Vt
        #pragma unroll
        for (int mi = 0; mi < 2; ++mi) {
            const int prow = w * 32 + mi * 16 + r16;
            const int fp = (r16 >> 2) & 3;
            short8 pf0 = *(const short8*)&Ps[prow][(g ^ fp) * 8];
            short8 pf1 = *(const short8*)&Ps[prow][((4 + g) ^ fp) * 8];
            #pragma unroll
            for (int dt = 0; dt < 4; ++dt) {
                short8 vf0 = *(const short8*)&Vt[dt * 16 + r16][g * 8];
                short8 vf1 = *(const short8*)&Vt[dt * 16 + r16][32 + g * 8];
                oacc[mi][dt] = __builtin_amdgcn_mfma_f32_16x16x32_bf16(pf0, vf0, oacc[mi][dt], 0, 0, 0);
                oacc[mi][dt] = __builtin_amdgcn_mfma_f32_16x16x32_bf16(pf1, vf1, oacc[mi][dt], 0, 0, 0);
            }
        }
    }

    // epilogue
    #pragma unroll
    for (int mi = 0; mi < 2; ++mi)
        #pragma unroll
        for (int jr = 0; jr < 4; ++jr) {
            const float inv = 1.f / l_r[mi][jr];
            const int row = q0 + w * 32 + mi * 16 + g * 4 + jr;
            unsigned short* dst = att + (size_t)(b * SEQ + row) * DIM + h * HDIM;
            #pragma unroll
            for (int dt = 0; dt < 4; ++dt)
                dst[dt * 16 + r16] = f2bf(oacc[mi][dt][jr] * inv);
        }
}

// ---------------------------------------------------------------------------
extern "C" void kernel_launch(void* const* d_in, const int* in_sizes, int n_in,
                              void* d_out, int out_size, void* d_ws, size_t ws_size,
                              hipStream_t stream)
{
    const float* x     = (const float*)d_in[0];
    const float* w_qkv = (const float*)d_in[1];
    const float* w_out = (const float*)d_in[2];
    const float* b_out = (const float*)d_in[3];
    float* out = (float*)d_out;

    // ws layout (ushort elems):
    //   qkv   [8192][3072]            @ 0          (48 MB)
    //   xb/att[8192][1024] (aliased)  @ 25165824   (16 MB)  xb dead before att written
    //   wqkvT [3072][1024]            @ 33554432   ( 6 MB)
    //   woutT [1024][1024]            @ 36700160   ( 2 MB)   total 72 MB
    unsigned short* qkv   = (unsigned short*)d_ws;
    unsigned short* xb    = qkv + 25165824;
    unsigned short* att   = xb;
    unsigned short* wqkvT = qkv + 33554432;
    unsigned short* woutT = qkv + 36700160;

    conv_kernel<<<dim3(ROWS * DIM / 4 / 256), 256, 0, stream>>>(x, xb, ROWS * DIM / 4);
    convT_kernel<<<dim3(QKV_N / 32, DIM / 32), 256, 0, stream>>>(w_qkv, wqkvT, DIM, QKV_N);
    convT_kernel<<<dim3(DIM / 32, DIM / 32), 256, 0, stream>>>(w_out, woutT, DIM, DIM);

    gemm_kernel<false><<<dim3(QKV_N / 128, ROWS / 128), 256, 0, stream>>>(
        xb, wqkvT, nullptr, qkv, ROWS, QKV_N, DIM);

    attn_kernel<<<dim3(SEQ / 128, NHEADS, BATCH), 256, 0, stream>>>(qkv, att);

    gemm_kernel<true><<<dim3(DIM / 128, ROWS / 128), 256, 0, stream>>>(
        att, woutT, b_out, out, ROWS, DIM, DIM);
}

// Round 4
// 245.871 us; speedup vs baseline: 10.5862x; 1.5543x over previous
//
#include <hip/hip_runtime.h>
#include <hip/hip_bf16.h>

typedef __attribute__((ext_vector_type(8))) short short8;
typedef __attribute__((ext_vector_type(4))) short short4v;
typedef __attribute__((ext_vector_type(4))) float f32x4;

#define DIM    1024
#define NHEADS 16
#define HDIM   64
#define SEQ    2048
#define BATCH  4
#define ROWS   8192            // BATCH*SEQ
#define QKV_N  3072            // 3*DIM

__device__ __forceinline__ unsigned short f2bf(float f) {
    union { float f; unsigned u; } v; v.f = f;
    unsigned u = v.u;
    return (unsigned short)((u + 0x7fffu + ((u >> 16) & 1u)) >> 16);   // RNE
}
__device__ __forceinline__ float bf2f(unsigned short h) {
    union { unsigned u; float f; } v; v.u = ((unsigned)h) << 16;
    return v.f;
}

// async global->LDS, 16B per lane; LDS dest = wave-uniform base + lane*16
__device__ __forceinline__ void gload16(const void* g, void* l) {
    __builtin_amdgcn_global_load_lds(
        (const __attribute__((address_space(1))) unsigned int*)g,
        (__attribute__((address_space(3))) unsigned int*)l, 16, 0, 0);
}

// ---------------------------------------------------------------------------
// convert fp32 -> bf16 (flat)
// ---------------------------------------------------------------------------
__global__ __launch_bounds__(256)
void conv_kernel(const float* __restrict__ src, unsigned short* __restrict__ dst, int n4)
{
    const int i = blockIdx.x * 256 + threadIdx.x;
    if (i >= n4) return;
    const float4 v = ((const float4*)src)[i];
    short4v o;
    o[0] = (short)f2bf(v.x); o[1] = (short)f2bf(v.y);
    o[2] = (short)f2bf(v.z); o[3] = (short)f2bf(v.w);
    ((short4v*)dst)[i] = o;
}

// ---------------------------------------------------------------------------
// transpose + convert: src [R][C] fp32 -> dst [C][R] bf16
// ---------------------------------------------------------------------------
__global__ __launch_bounds__(256)
void convT_kernel(const float* __restrict__ src, unsigned short* __restrict__ dst,
                  int R, int C)
{
    __shared__ float T[32][33];
    const int r0 = blockIdx.y * 32, c0 = blockIdx.x * 32;
    const int tc = threadIdx.x & 31, tr = threadIdx.x >> 5;   // 32 x 8
    #pragma unroll
    for (int i = 0; i < 4; ++i)
        T[tr + i * 8][tc] = src[(size_t)(r0 + tr + i * 8) * C + c0 + tc];
    __syncthreads();
    #pragma unroll
    for (int i = 0; i < 4; ++i)
        dst[(size_t)(c0 + tr + i * 8) * R + r0 + tc] = f2bf(T[tc][tr + i * 8]);
}

// ---------------------------------------------------------------------------
// bf16 MFMA GEMM (m97 structure): C[M,N] = A[M,K] @ BT[N,K]^T (+bias).
// 128x128 tile, BK=32, 256 thr = 4 waves (2x2), 4x4 16x16x32 frags per wave.
// ---------------------------------------------------------------------------
template<bool WITH_BIAS>
__global__ __launch_bounds__(256)
void gemm_kernel(const unsigned short* __restrict__ A,   // [M][K] bf16
                 const unsigned short* __restrict__ BT,  // [N][K] bf16
                 const float* __restrict__ bias,
                 void* __restrict__ Cp, int M, int N, int K)
{
    __shared__ alignas(16) unsigned short LA[128][32];
    __shared__ alignas(16) unsigned short LB[128][32];

    const int tid  = threadIdx.x;
    const int lane = tid & 63;
    const int w    = tid >> 6;
    const int wr   = w >> 1, wc = w & 1;
    const int bm   = blockIdx.y * 128, bn = blockIdx.x * 128;
    const int r16  = lane & 15, g = lane >> 4;

    f32x4 acc[4][4] = {};

    const int srow = lane >> 2, skg = (lane & 3) * 8;

    for (int k0 = 0; k0 < K; k0 += 32) {
        #pragma unroll
        for (int c = 0; c < 2; ++c) {
            const int chunk = w * 2 + c;            // 8 chunks over 4 waves
            gload16(A  + (size_t)(bm + chunk * 16 + srow) * K + k0 + skg, &LA[chunk * 16][0]);
            gload16(BT + (size_t)(bn + chunk * 16 + srow) * K + k0 + skg, &LB[chunk * 16][0]);
        }
        __syncthreads();
        short8 af[4], bf_[4];
        #pragma unroll
        for (int i = 0; i < 4; ++i) {
            af[i]  = *(const short8*)&LA[wr * 64 + i * 16 + r16][g * 8];
            bf_[i] = *(const short8*)&LB[wc * 64 + i * 16 + r16][g * 8];
        }
        #pragma unroll
        for (int mi = 0; mi < 4; ++mi)
            #pragma unroll
            for (int ni = 0; ni < 4; ++ni)
                acc[mi][ni] = __builtin_amdgcn_mfma_f32_16x16x32_bf16(
                    af[mi], bf_[ni], acc[mi][ni], 0, 0, 0);
        __syncthreads();
    }

    #pragma unroll
    for (int mi = 0; mi < 4; ++mi)
        #pragma unroll
        for (int ni = 0; ni < 4; ++ni) {
            const int gcol = bn + wc * 64 + ni * 16 + r16;
            #pragma unroll
            for (int j = 0; j < 4; ++j) {
                const int grow = bm + wr * 64 + mi * 16 + g * 4 + j;
                const float v = acc[mi][ni][j];
                if (WITH_BIAS)
                    ((float*)Cp)[(size_t)grow * N + gcol] = v + bias[gcol];
                else
                    ((unsigned short*)Cp)[(size_t)grow * N + gcol] = f2bf(v);
            }
        }
}

// ---------------------------------------------------------------------------
// MFMA flash attention, SWAPPED-operand form. Block = 256 thr (4 waves) =
// 128 q-rows of one (b,h). Wave w: q in [w*32, w*32+32), 2 fragments (mi).
// K-tiles of 64 keys.
//
// QK^T computed as mfma(K-frag, Q-frag) -> C[row=key][col=q]: lane (q=l&15,
// g=l>>4) holds S[q][key= jt*16+g*4+jr] -- the 64-key row is spread over only
// the 4 lanes sharing q -> softmax = in-register tree + 2 shfl_xor.
//
// PV: key order within a tile is irrelevant (softmax+sum commute), so V^T is
// stored KEY-PERMUTED such that each lane's own 16 P-values are exactly the
// B-fragment it must supply: pos(key): jt*16+g*4+jr -> (g*8 + (jt&1)*4 + jr)
// + (jt>>1)*32. P never touches LDS; zero shuffles; 3rd barrier removed.
// ---------------------------------------------------------------------------
__global__ __launch_bounds__(256, 4)
void attn_kernel(const unsigned short* __restrict__ qkv,
                 unsigned short* __restrict__ att)
{
    __shared__ alignas(16) unsigned short Ks[64][64];   // linear (gload_lds dest)
    __shared__ alignas(16) unsigned short Vt[64][80];   // [d][pos]  (permuted keys)

    const int tid  = threadIdx.x;
    const int lane = tid & 63;
    const int w    = tid >> 6;
    const int b  = blockIdx.z, h = blockIdx.y;
    const int q0 = blockIdx.x * 128;
    const size_t base = (size_t)b * SEQ * QKV_N + (size_t)h * HDIM;

    const int r16 = lane & 15;
    const int g   = lane >> 4;
    const int f7  = r16 & 7;

    // Q fragments (B operand): col=q=r16, elements d = g*8+j (+32)
    short8 qf[2][2];
    #pragma unroll
    for (int mi = 0; mi < 2; ++mi) {
        const unsigned short* qrow =
            qkv + base + (size_t)(q0 + w * 32 + mi * 16 + r16) * QKV_N;
        qf[mi][0] = *(const short8*)(qrow + g * 8);
        qf[mi][1] = *(const short8*)(qrow + 32 + g * 8);
    }

    f32x4 oacc[2][4] = {};          // [mi][dt]: col q=r16, row d=dt*16+g*4+j
    float m_r[2] = { -3e38f, -3e38f };
    float l_r[2] = { 0.f, 0.f };

    // K staging: chunk c covers keys c*8..c*8+7; lane: row +(l>>3), pre-swizzled grp
    const int krow  = lane >> 3;
    const int kGsrc = (lane & 7) ^ (krow & 7);

    // V staging: lane = key (kt+lane); permuted dest column pos(lane)
    const int k5 = lane & 31, khi = lane >> 5;
    const int vpos = ((k5 < 16) ? ((k5 >> 2) * 8 + (k5 & 3))
                                : (((k5 - 16) >> 2) * 8 + 4 + ((k5 - 16) & 3)))
                     + khi * 32;

    for (int kt = 0; kt < SEQ; kt += 64) {
        __syncthreads();   // prev tile fully consumed
        #pragma unroll
        for (int c = 0; c < 2; ++c) {
            const int chunk = w * 2 + c;
            const unsigned short* gsrc =
                qkv + base + (size_t)(kt + chunk * 8 + krow) * QKV_N + DIM + kGsrc * 8;
            gload16(gsrc, &Ks[chunk * 8][0]);
        }
        {   // stage V transposed+permuted: wave w covers d [w*16,+16)
            const unsigned short* vsrc =
                qkv + base + (size_t)(kt + lane) * QKV_N + 2 * DIM + w * 16;
            short8 v0 = *(const short8*)(vsrc);
            short8 v1 = *(const short8*)(vsrc + 8);
            #pragma unroll
            for (int i = 0; i < 8; ++i) {
                Vt[w * 16 + i][vpos]     = (unsigned short)v0[i];
                Vt[w * 16 + 8 + i][vpos] = (unsigned short)v1[i];
            }
        }
        __syncthreads();

        // --- S^T = K Q^T : C[key][q]
        f32x4 sacc[2][4] = {};
        #pragma unroll
        for (int jt = 0; jt < 4; ++jt) {
            const int row = jt * 16 + r16;
            short8 kf0 = *(const short8*)&Ks[row][(g ^ f7) * 8];
            short8 kf1 = *(const short8*)&Ks[row][((4 + g) ^ f7) * 8];
            sacc[0][jt] = __builtin_amdgcn_mfma_f32_16x16x32_bf16(kf0, qf[0][0], sacc[0][jt], 0, 0, 0);
            sacc[0][jt] = __builtin_amdgcn_mfma_f32_16x16x32_bf16(kf1, qf[0][1], sacc[0][jt], 0, 0, 0);
            sacc[1][jt] = __builtin_amdgcn_mfma_f32_16x16x32_bf16(kf0, qf[1][0], sacc[1][jt], 0, 0, 0);
            sacc[1][jt] = __builtin_amdgcn_mfma_f32_16x16x32_bf16(kf1, qf[1][1], sacc[1][jt], 0, 0, 0);
        }

        // --- softmax (register-local rows) + build lane-local P fragments
        short8 pb[2][2];
        float fs[2];
        #pragma unroll
        for (int mi = 0; mi < 2; ++mi) {
            float tm = sacc[mi][0][0];
            #pragma unroll
            for (int jt = 0; jt < 4; ++jt)
                #pragma unroll
                for (int jr = 0; jr < 4; ++jr)
                    tm = fmaxf(tm, sacc[mi][jt][jr]);
            tm = fmaxf(tm, __shfl_xor(tm, 16));
            tm = fmaxf(tm, __shfl_xor(tm, 32));
            tm *= 0.125f;
            const float nm = fmaxf(m_r[mi], tm);
            const float f  = __expf(m_r[mi] - nm);
            m_r[mi] = nm;
            fs[mi] = f;

            float ps = 0.f;
            unsigned pw[8];
            #pragma unroll
            for (int jt = 0; jt < 4; ++jt) {
                const float p0 = __expf(sacc[mi][jt][0] * 0.125f - nm);
                const float p1 = __expf(sacc[mi][jt][1] * 0.125f - nm);
                const float p2 = __expf(sacc[mi][jt][2] * 0.125f - nm);
                const float p3 = __expf(sacc[mi][jt][3] * 0.125f - nm);
                ps += (p0 + p1) + (p2 + p3);
                pw[jt * 2]     = (unsigned)f2bf(p0) | ((unsigned)f2bf(p1) << 16);
                pw[jt * 2 + 1] = (unsigned)f2bf(p2) | ((unsigned)f2bf(p3) << 16);
            }
            ps += __shfl_xor(ps, 16);
            ps += __shfl_xor(ps, 32);
            l_r[mi] = l_r[mi] * f + ps;

            union { unsigned u[4]; short8 s; } c0, c1;
            c0.u[0] = pw[0]; c0.u[1] = pw[1]; c0.u[2] = pw[2]; c0.u[3] = pw[3];
            c1.u[0] = pw[4]; c1.u[1] = pw[5]; c1.u[2] = pw[6]; c1.u[3] = pw[7];
            pb[mi][0] = c0.s;   // keys (perm. positions) 0..31
            pb[mi][1] = c1.s;   // keys 32..63
        }
        #pragma unroll
        for (int mi = 0; mi < 2; ++mi)
            #pragma unroll
            for (int dt = 0; dt < 4; ++dt)
                #pragma unroll
                for (int jr = 0; jr < 4; ++jr)
                    oacc[mi][dt][jr] *= fs[mi];

        // --- O^T += V^T P^T : A = Vt (permuted), B = pb (lane-local)
        #pragma unroll
        for (int dt = 0; dt < 4; ++dt) {
            short8 vf0 = *(const short8*)&Vt[dt * 16 + r16][g * 8];
            short8 vf1 = *(const short8*)&Vt[dt * 16 + r16][32 + g * 8];
            #pragma unroll
            for (int mi = 0; mi < 2; ++mi) {
                oacc[mi][dt] = __builtin_amdgcn_mfma_f32_16x16x32_bf16(vf0, pb[mi][0], oacc[mi][dt], 0, 0, 0);
                oacc[mi][dt] = __builtin_amdgcn_mfma_f32_16x16x32_bf16(vf1, pb[mi][1], oacc[mi][dt], 0, 0, 0);
            }
        }
    }

    // epilogue: O^T[d][q] -> att[q][h*64+d]
    #pragma unroll
    for (int mi = 0; mi < 2; ++mi) {
        const float inv = 1.f / l_r[mi];
        const int q = q0 + w * 32 + mi * 16 + r16;
        unsigned short* dst = att + (size_t)(b * SEQ + q) * DIM + h * HDIM;
        #pragma unroll
        for (int dt = 0; dt < 4; ++dt)
            #pragma unroll
            for (int jr = 0; jr < 4; ++jr)
                dst[dt * 16 + g * 4 + jr] = f2bf(oacc[mi][dt][jr] * inv);
    }
}

// ---------------------------------------------------------------------------
extern "C" void kernel_launch(void* const* d_in, const int* in_sizes, int n_in,
                              void* d_out, int out_size, void* d_ws, size_t ws_size,
                              hipStream_t stream)
{
    const float* x     = (const float*)d_in[0];
    const float* w_qkv = (const float*)d_in[1];
    const float* w_out = (const float*)d_in[2];
    const float* b_out = (const float*)d_in[3];
    float* out = (float*)d_out;

    unsigned short* qkv   = (unsigned short*)d_ws;      // [8192][3072]
    unsigned short* xb    = qkv + 25165824;             // [8192][1024] (aliased w/ att)
    unsigned short* att   = xb;
    unsigned short* wqkvT = qkv + 33554432;             // [3072][1024]
    unsigned short* woutT = qkv + 36700160;             // [1024][1024]

    conv_kernel<<<dim3(ROWS * DIM / 4 / 256), 256, 0, stream>>>(x, xb, ROWS * DIM / 4);
    convT_kernel<<<dim3(QKV_N / 32, DIM / 32), 256, 0, stream>>>(w_qkv, wqkvT, DIM, QKV_N);
    convT_kernel<<<dim3(DIM / 32, DIM / 32), 256, 0, stream>>>(w_out, woutT, DIM, DIM);

    gemm_kernel<false><<<dim3(QKV_N / 128, ROWS / 128), 256, 0, stream>>>(
        xb, wqkvT, nullptr, qkv, ROWS, QKV_N, DIM);

    attn_kernel<<<dim3(SEQ / 128, NHEADS, BATCH), 256, 0, stream>>>(qkv, att);

    gemm_kernel<true><<<dim3(DIM / 128, ROWS / 128), 256, 0, stream>>>(
        att, woutT, b_out, out, ROWS, DIM, DIM);
}

// Round 5
// 224.504 us; speedup vs baseline: 11.5937x; 1.0952x over previous
//
#include <hip/hip_runtime.h>
#include <hip/hip_bf16.h>

typedef __attribute__((ext_vector_type(8))) short short8;
typedef __attribute__((ext_vector_type(4))) short short4v;
typedef __attribute__((ext_vector_type(4))) float f32x4;

#define DIM    1024
#define NHEADS 16
#define HDIM   64
#define SEQ    2048
#define BATCH  4
#define ROWS   8192            // BATCH*SEQ
#define QKV_N  3072            // 3*DIM

// 0.125 * log2(e): folds attention scale AND exp->exp2 conversion into Q
#define QSCALE_LOG2E 0.18033688011112042f

__device__ __forceinline__ unsigned short f2bf(float f) {
    union { float f; unsigned u; } v; v.f = f;
    unsigned u = v.u;
    return (unsigned short)((u + 0x7fffu + ((u >> 16) & 1u)) >> 16);   // RNE
}
__device__ __forceinline__ unsigned short f2bf_n(float f) {          // native cast
    union { __hip_bfloat16 h; unsigned short u; } v;
    v.h = __float2bfloat16(f);
    return v.u;
}
__device__ __forceinline__ float exp2_fast(float x) {                // v_exp_f32 = 2^x
    float r;
    asm("v_exp_f32 %0, %1" : "=v"(r) : "v"(x));
    return r;
}

// async global->LDS, 16B per lane; LDS dest = wave-uniform base + lane*16
__device__ __forceinline__ void gload16(const void* g, void* l) {
    __builtin_amdgcn_global_load_lds(
        (const __attribute__((address_space(1))) unsigned int*)g,
        (__attribute__((address_space(3))) unsigned int*)l, 16, 0, 0);
}

// ---------------------------------------------------------------------------
// convert fp32 -> bf16 (flat)
// ---------------------------------------------------------------------------
__global__ __launch_bounds__(256)
void conv_kernel(const float* __restrict__ src, unsigned short* __restrict__ dst, int n4)
{
    const int i = blockIdx.x * 256 + threadIdx.x;
    if (i >= n4) return;
    const float4 v = ((const float4*)src)[i];
    short4v o;
    o[0] = (short)f2bf(v.x); o[1] = (short)f2bf(v.y);
    o[2] = (short)f2bf(v.z); o[3] = (short)f2bf(v.w);
    ((short4v*)dst)[i] = o;
}

// ---------------------------------------------------------------------------
// transpose + convert: src [R][C] fp32 -> dst [C][R] bf16
// ---------------------------------------------------------------------------
__global__ __launch_bounds__(256)
void convT_kernel(const float* __restrict__ src, unsigned short* __restrict__ dst,
                  int R, int C)
{
    __shared__ float T[32][33];
    const int r0 = blockIdx.y * 32, c0 = blockIdx.x * 32;
    const int tc = threadIdx.x & 31, tr = threadIdx.x >> 5;   // 32 x 8
    #pragma unroll
    for (int i = 0; i < 4; ++i)
        T[tr + i * 8][tc] = src[(size_t)(r0 + tr + i * 8) * C + c0 + tc];
    __syncthreads();
    #pragma unroll
    for (int i = 0; i < 4; ++i)
        dst[(size_t)(c0 + tr + i * 8) * R + r0 + tc] = f2bf(T[tc][tr + i * 8]);
}

// ---------------------------------------------------------------------------
// bf16 MFMA GEMM (m97 structure): C[M,N] = A[M,K] @ BT[N,K]^T (+bias).
// 128x128 tile, BK=32, 256 thr = 4 waves (2x2), 4x4 16x16x32 frags per wave.
// QSCALE: multiply cols < DIM (the Q third of qkv) by 0.125*log2e (folded
// attention scale + exp2 conversion).
// ---------------------------------------------------------------------------
template<bool WITH_BIAS, bool QSCALE>
__global__ __launch_bounds__(256)
void gemm_kernel(const unsigned short* __restrict__ A,   // [M][K] bf16
                 const unsigned short* __restrict__ BT,  // [N][K] bf16
                 const float* __restrict__ bias,
                 void* __restrict__ Cp, int M, int N, int K)
{
    __shared__ alignas(16) unsigned short LA[128][32];
    __shared__ alignas(16) unsigned short LB[128][32];

    const int tid  = threadIdx.x;
    const int lane = tid & 63;
    const int w    = tid >> 6;
    const int wr   = w >> 1, wc = w & 1;
    const int bm   = blockIdx.y * 128, bn = blockIdx.x * 128;
    const int r16  = lane & 15, g = lane >> 4;

    f32x4 acc[4][4] = {};

    const int srow = lane >> 2, skg = (lane & 3) * 8;

    for (int k0 = 0; k0 < K; k0 += 32) {
        #pragma unroll
        for (int c = 0; c < 2; ++c) {
            const int chunk = w * 2 + c;            // 8 chunks over 4 waves
            gload16(A  + (size_t)(bm + chunk * 16 + srow) * K + k0 + skg, &LA[chunk * 16][0]);
            gload16(BT + (size_t)(bn + chunk * 16 + srow) * K + k0 + skg, &LB[chunk * 16][0]);
        }
        __syncthreads();
        short8 af[4], bf_[4];
        #pragma unroll
        for (int i = 0; i < 4; ++i) {
            af[i]  = *(const short8*)&LA[wr * 64 + i * 16 + r16][g * 8];
            bf_[i] = *(const short8*)&LB[wc * 64 + i * 16 + r16][g * 8];
        }
        __builtin_amdgcn_s_setprio(1);
        #pragma unroll
        for (int mi = 0; mi < 4; ++mi)
            #pragma unroll
            for (int ni = 0; ni < 4; ++ni)
                acc[mi][ni] = __builtin_amdgcn_mfma_f32_16x16x32_bf16(
                    af[mi], bf_[ni], acc[mi][ni], 0, 0, 0);
        __builtin_amdgcn_s_setprio(0);
        __syncthreads();
    }

    #pragma unroll
    for (int mi = 0; mi < 4; ++mi)
        #pragma unroll
        for (int ni = 0; ni < 4; ++ni) {
            const int gcol = bn + wc * 64 + ni * 16 + r16;
            #pragma unroll
            for (int j = 0; j < 4; ++j) {
                const int grow = bm + wr * 64 + mi * 16 + g * 4 + j;
                float v = acc[mi][ni][j];
                if (QSCALE && gcol < DIM) v *= QSCALE_LOG2E;
                if (WITH_BIAS)
                    ((float*)Cp)[(size_t)grow * N + gcol] = v + bias[gcol];
                else
                    ((unsigned short*)Cp)[(size_t)grow * N + gcol] = f2bf(v);
            }
        }
}

// ---------------------------------------------------------------------------
// MFMA flash attention, SWAPPED-operand form, exp2-domain softmax.
// Q was pre-scaled by 0.125*log2e in gemm1, so sacc is directly the exp2
// exponent. Block = 256 thr (4 waves) = 128 q-rows of one (b,h).
// Wave w: q in [w*32,+32), 2 fragments (mi). K-tiles of 64 keys.
//
// mfma(K,Q) -> C[key][q]: lane holds 16 S-values of ONE q -> softmax is
// register-local + 2 shfl. V^T stored key-permuted so each lane's P values
// form its PV B-fragment directly (no LDS round-trip for P).
// Defer-max (T13, THR=8): skip O-rescale while tile max stays within 8
// of the running max (P bounded by 2^8; exact online-softmax identity).
// ---------------------------------------------------------------------------
__global__ __launch_bounds__(256, 4)
void attn_kernel(const unsigned short* __restrict__ qkv,
                 unsigned short* __restrict__ att)
{
    __shared__ alignas(16) unsigned short Ks[64][64];   // linear (gload_lds dest)
    __shared__ alignas(16) unsigned short Vt[64][80];   // [d][pos]  (permuted keys)

    const int tid  = threadIdx.x;
    const int lane = tid & 63;
    const int w    = tid >> 6;
    const int b  = blockIdx.z, h = blockIdx.y;
    const int q0 = blockIdx.x * 128;
    const size_t base = (size_t)b * SEQ * QKV_N + (size_t)h * HDIM;

    const int r16 = lane & 15;
    const int g   = lane >> 4;
    const int f7  = r16 & 7;

    // Q fragments (B operand): col=q=r16, elements d = g*8+j (+32)
    short8 qf[2][2];
    #pragma unroll
    for (int mi = 0; mi < 2; ++mi) {
        const unsigned short* qrow =
            qkv + base + (size_t)(q0 + w * 32 + mi * 16 + r16) * QKV_N;
        qf[mi][0] = *(const short8*)(qrow + g * 8);
        qf[mi][1] = *(const short8*)(qrow + 32 + g * 8);
    }

    f32x4 oacc[2][4] = {};          // [mi][dt]: col q=r16, row d=dt*16+g*4+j
    float m_r[2] = { -3e38f, -3e38f };
    float l_r[2] = { 0.f, 0.f };

    // K staging: chunk c covers keys c*8..c*8+7; pre-swizzled source group
    const int krow  = lane >> 3;
    const int kGsrc = (lane & 7) ^ (krow & 7);

    // V staging: lane = key; permuted dest column pos(lane)
    const int k5 = lane & 31, khi = lane >> 5;
    const int vpos = ((k5 < 16) ? ((k5 >> 2) * 8 + (k5 & 3))
                                : (((k5 - 16) >> 2) * 8 + 4 + ((k5 - 16) & 3)))
                     + khi * 32;

    for (int kt = 0; kt < SEQ; kt += 64) {
        __syncthreads();   // prev tile fully consumed
        #pragma unroll
        for (int c = 0; c < 2; ++c) {
            const int chunk = w * 2 + c;
            const unsigned short* gsrc =
                qkv + base + (size_t)(kt + chunk * 8 + krow) * QKV_N + DIM + kGsrc * 8;
            gload16(gsrc, &Ks[chunk * 8][0]);
        }
        {   // stage V transposed+permuted: wave w covers d [w*16,+16)
            const unsigned short* vsrc =
                qkv + base + (size_t)(kt + lane) * QKV_N + 2 * DIM + w * 16;
            short8 v0 = *(const short8*)(vsrc);
            short8 v1 = *(const short8*)(vsrc + 8);
            #pragma unroll
            for (int i = 0; i < 8; ++i) {
                Vt[w * 16 + i][vpos]     = (unsigned short)v0[i];
                Vt[w * 16 + 8 + i][vpos] = (unsigned short)v1[i];
            }
        }
        __syncthreads();

        // --- S^T = K Q^T : C[key][q]  (sacc already in exp2 domain)
        f32x4 sacc[2][4] = {};
        __builtin_amdgcn_s_setprio(1);
        #pragma unroll
        for (int jt = 0; jt < 4; ++jt) {
            const int row = jt * 16 + r16;
            short8 kf0 = *(const short8*)&Ks[row][(g ^ f7) * 8];
            short8 kf1 = *(const short8*)&Ks[row][((4 + g) ^ f7) * 8];
            sacc[0][jt] = __builtin_amdgcn_mfma_f32_16x16x32_bf16(kf0, qf[0][0], sacc[0][jt], 0, 0, 0);
            sacc[0][jt] = __builtin_amdgcn_mfma_f32_16x16x32_bf16(kf1, qf[0][1], sacc[0][jt], 0, 0, 0);
            sacc[1][jt] = __builtin_amdgcn_mfma_f32_16x16x32_bf16(kf0, qf[1][0], sacc[1][jt], 0, 0, 0);
            sacc[1][jt] = __builtin_amdgcn_mfma_f32_16x16x32_bf16(kf1, qf[1][1], sacc[1][jt], 0, 0, 0);
        }
        __builtin_amdgcn_s_setprio(0);

        // --- softmax (register-local rows, exp2 domain) + lane-local P frags
        short8 pb[2][2];
        #pragma unroll
        for (int mi = 0; mi < 2; ++mi) {
            float tm = fmaxf(fmaxf(sacc[mi][0][0], sacc[mi][0][1]),
                             fmaxf(sacc[mi][0][2], sacc[mi][0][3]));
            #pragma unroll
            for (int jt = 1; jt < 4; ++jt) {
                tm = fmaxf(tm, fmaxf(fmaxf(sacc[mi][jt][0], sacc[mi][jt][1]),
                                     fmaxf(sacc[mi][jt][2], sacc[mi][jt][3])));
            }
            tm = fmaxf(tm, __shfl_xor(tm, 16));
            tm = fmaxf(tm, __shfl_xor(tm, 32));

            float nm = m_r[mi];
            if (!__all(tm <= m_r[mi] + 8.f)) {       // T13 defer-max, THR=8
                nm = fmaxf(m_r[mi], tm);
                const float f = exp2_fast(m_r[mi] - nm);
                m_r[mi] = nm;
                l_r[mi] *= f;
                #pragma unroll
                for (int dt = 0; dt < 4; ++dt)
                    #pragma unroll
                    for (int jr = 0; jr < 4; ++jr)
                        oacc[mi][dt][jr] *= f;
            }

            float ps = 0.f;
            unsigned pw[8];
            #pragma unroll
            for (int jt = 0; jt < 4; ++jt) {
                const float p0 = exp2_fast(sacc[mi][jt][0] - nm);
                const float p1 = exp2_fast(sacc[mi][jt][1] - nm);
                const float p2 = exp2_fast(sacc[mi][jt][2] - nm);
                const float p3 = exp2_fast(sacc[mi][jt][3] - nm);
                ps += (p0 + p1) + (p2 + p3);
                pw[jt * 2]     = (unsigned)f2bf_n(p0) | ((unsigned)f2bf_n(p1) << 16);
                pw[jt * 2 + 1] = (unsigned)f2bf_n(p2) | ((unsigned)f2bf_n(p3) << 16);
            }
            ps += __shfl_xor(ps, 16);
            ps += __shfl_xor(ps, 32);
            l_r[mi] += ps;

            union { unsigned u[4]; short8 s; } c0, c1;
            c0.u[0] = pw[0]; c0.u[1] = pw[1]; c0.u[2] = pw[2]; c0.u[3] = pw[3];
            c1.u[0] = pw[4]; c1.u[1] = pw[5]; c1.u[2] = pw[6]; c1.u[3] = pw[7];
            pb[mi][0] = c0.s;   // keys (perm. positions) 0..31
            pb[mi][1] = c1.s;   // keys 32..63
        }

        // --- O^T += V^T P^T : A = Vt (permuted), B = pb (lane-local)
        __builtin_amdgcn_s_setprio(1);
        #pragma unroll
        for (int dt = 0; dt < 4; ++dt) {
            short8 vf0 = *(const short8*)&Vt[dt * 16 + r16][g * 8];
            short8 vf1 = *(const short8*)&Vt[dt * 16 + r16][32 + g * 8];
            #pragma unroll
            for (int mi = 0; mi < 2; ++mi) {
                oacc[mi][dt] = __builtin_amdgcn_mfma_f32_16x16x32_bf16(vf0, pb[mi][0], oacc[mi][dt], 0, 0, 0);
                oacc[mi][dt] = __builtin_amdgcn_mfma_f32_16x16x32_bf16(vf1, pb[mi][1], oacc[mi][dt], 0, 0, 0);
            }
        }
        __builtin_amdgcn_s_setprio(0);
    }

    // epilogue: O^T[d][q] -> att[q][h*64+d]
    #pragma unroll
    for (int mi = 0; mi < 2; ++mi) {
        const float inv = 1.f / l_r[mi];
        const int q = q0 + w * 32 + mi * 16 + r16;
        unsigned short* dst = att + (size_t)(b * SEQ + q) * DIM + h * HDIM;
        #pragma unroll
        for (int dt = 0; dt < 4; ++dt)
            #pragma unroll
            for (int jr = 0; jr < 4; ++jr)
                dst[dt * 16 + g * 4 + jr] = f2bf(oacc[mi][dt][jr] * inv);
    }
}

// ---------------------------------------------------------------------------
extern "C" void kernel_launch(void* const* d_in, const int* in_sizes, int n_in,
                              void* d_out, int out_size, void* d_ws, size_t ws_size,
                              hipStream_t stream)
{
    const float* x     = (const float*)d_in[0];
    const float* w_qkv = (const float*)d_in[1];
    const float* w_out = (const float*)d_in[2];
    const float* b_out = (const float*)d_in[3];
    float* out = (float*)d_out;

    unsigned short* qkv   = (unsigned short*)d_ws;      // [8192][3072]
    unsigned short* xb    = qkv + 25165824;             // [8192][1024] (aliased w/ att)
    unsigned short* att   = xb;
    unsigned short* wqkvT = qkv + 33554432;             // [3072][1024]
    unsigned short* woutT = qkv + 36700160;             // [1024][1024]

    conv_kernel<<<dim3(ROWS * DIM / 4 / 256), 256, 0, stream>>>(x, xb, ROWS * DIM / 4);
    convT_kernel<<<dim3(QKV_N / 32, DIM / 32), 256, 0, stream>>>(w_qkv, wqkvT, DIM, QKV_N);
    convT_kernel<<<dim3(DIM / 32, DIM / 32), 256, 0, stream>>>(w_out, woutT, DIM, DIM);

    gemm_kernel<false, true><<<dim3(QKV_N / 128, ROWS / 128), 256, 0, stream>>>(
        xb, wqkvT, nullptr, qkv, ROWS, QKV_N, DIM);

    attn_kernel<<<dim3(SEQ / 128, NHEADS, BATCH), 256, 0, stream>>>(qkv, att);

    gemm_kernel<true, false><<<dim3(DIM / 128, ROWS / 128), 256, 0, stream>>>(
        att, woutT, b_out, out, ROWS, DIM, DIM);
}

// Round 6
// 208.538 us; speedup vs baseline: 12.4813x; 1.0766x over previous
//
#include <hip/hip_runtime.h>
#include <hip/hip_bf16.h>

typedef __attribute__((ext_vector_type(8))) short short8;
typedef __attribute__((ext_vector_type(4))) short short4v;
typedef __attribute__((ext_vector_type(4))) float f32x4;

#define DIM    1024
#define NHEADS 16
#define HDIM   64
#define SEQ    2048
#define BATCH  4
#define ROWS   8192            // BATCH*SEQ
#define QKV_N  3072            // 3*DIM

// 0.125 * log2(e): folds attention scale AND exp->exp2 conversion into Q
#define QSCALE_LOG2E 0.18033688011112042f

__device__ __forceinline__ unsigned short f2bf(float f) {
    union { float f; unsigned u; } v; v.f = f;
    unsigned u = v.u;
    return (unsigned short)((u + 0x7fffu + ((u >> 16) & 1u)) >> 16);   // RNE
}
__device__ __forceinline__ float exp2_fast(float x) {                // v_exp_f32 = 2^x
    float r;
    asm("v_exp_f32 %0, %1" : "=v"(r) : "v"(x));
    return r;
}
// packed f32x2 -> bf16x2 (lo = a, hi = b); no builtin on gfx950 (T12)
__device__ __forceinline__ unsigned cvt_pk_bf16(float a, float b) {
    unsigned r;
    asm("v_cvt_pk_bf16_f32 %0, %1, %2" : "=v"(r) : "v"(a), "v"(b));
    return r;
}

// async global->LDS, 16B per lane; LDS dest = wave-uniform base + lane*16
__device__ __forceinline__ void gload16(const void* g, void* l) {
    __builtin_amdgcn_global_load_lds(
        (const __attribute__((address_space(1))) unsigned int*)g,
        (__attribute__((address_space(3))) unsigned int*)l, 16, 0, 0);
}

// ---------------------------------------------------------------------------
// convert fp32 -> bf16 (flat)
// ---------------------------------------------------------------------------
__global__ __launch_bounds__(256)
void conv_kernel(const float* __restrict__ src, unsigned short* __restrict__ dst, int n4)
{
    const int i = blockIdx.x * 256 + threadIdx.x;
    if (i >= n4) return;
    const float4 v = ((const float4*)src)[i];
    short4v o;
    o[0] = (short)f2bf(v.x); o[1] = (short)f2bf(v.y);
    o[2] = (short)f2bf(v.z); o[3] = (short)f2bf(v.w);
    ((short4v*)dst)[i] = o;
}

// ---------------------------------------------------------------------------
// transpose + convert: src [R][C] fp32 -> dst [C][R] bf16
// ---------------------------------------------------------------------------
__global__ __launch_bounds__(256)
void convT_kernel(const float* __restrict__ src, unsigned short* __restrict__ dst,
                  int R, int C)
{
    __shared__ float T[32][33];
    const int r0 = blockIdx.y * 32, c0 = blockIdx.x * 32;
    const int tc = threadIdx.x & 31, tr = threadIdx.x >> 5;   // 32 x 8
    #pragma unroll
    for (int i = 0; i < 4; ++i)
        T[tr + i * 8][tc] = src[(size_t)(r0 + tr + i * 8) * C + c0 + tc];
    __syncthreads();
    #pragma unroll
    for (int i = 0; i < 4; ++i)
        dst[(size_t)(c0 + tr + i * 8) * R + r0 + tc] = f2bf(T[tc][tr + i * 8]);
}

// ---------------------------------------------------------------------------
// bf16 MFMA GEMM (m97 structure): C[M,N] = A[M,K] @ BT[N,K]^T (+bias).
// 128x128 tile, BK=32, 256 thr = 4 waves (2x2), 4x4 16x16x32 frags per wave.
// QSCALE: multiply cols < DIM (the Q third of qkv) by 0.125*log2e.
// ---------------------------------------------------------------------------
template<bool WITH_BIAS, bool QSCALE>
__global__ __launch_bounds__(256)
void gemm_kernel(const unsigned short* __restrict__ A,   // [M][K] bf16
                 const unsigned short* __restrict__ BT,  // [N][K] bf16
                 const float* __restrict__ bias,
                 void* __restrict__ Cp, int M, int N, int K)
{
    __shared__ alignas(16) unsigned short LA[128][32];
    __shared__ alignas(16) unsigned short LB[128][32];

    const int tid  = threadIdx.x;
    const int lane = tid & 63;
    const int w    = tid >> 6;
    const int wr   = w >> 1, wc = w & 1;
    const int bm   = blockIdx.y * 128, bn = blockIdx.x * 128;
    const int r16  = lane & 15, g = lane >> 4;

    f32x4 acc[4][4] = {};

    const int srow = lane >> 2, skg = (lane & 3) * 8;

    for (int k0 = 0; k0 < K; k0 += 32) {
        #pragma unroll
        for (int c = 0; c < 2; ++c) {
            const int chunk = w * 2 + c;            // 8 chunks over 4 waves
            gload16(A  + (size_t)(bm + chunk * 16 + srow) * K + k0 + skg, &LA[chunk * 16][0]);
            gload16(BT + (size_t)(bn + chunk * 16 + srow) * K + k0 + skg, &LB[chunk * 16][0]);
        }
        __syncthreads();
        short8 af[4], bf_[4];
        #pragma unroll
        for (int i = 0; i < 4; ++i) {
            af[i]  = *(const short8*)&LA[wr * 64 + i * 16 + r16][g * 8];
            bf_[i] = *(const short8*)&LB[wc * 64 + i * 16 + r16][g * 8];
        }
        __builtin_amdgcn_s_setprio(1);
        #pragma unroll
        for (int mi = 0; mi < 4; ++mi)
            #pragma unroll
            for (int ni = 0; ni < 4; ++ni)
                acc[mi][ni] = __builtin_amdgcn_mfma_f32_16x16x32_bf16(
                    af[mi], bf_[ni], acc[mi][ni], 0, 0, 0);
        __builtin_amdgcn_s_setprio(0);
        __syncthreads();
    }

    #pragma unroll
    for (int mi = 0; mi < 4; ++mi)
        #pragma unroll
        for (int ni = 0; ni < 4; ++ni) {
            const int gcol = bn + wc * 64 + ni * 16 + r16;
            #pragma unroll
            for (int j = 0; j < 4; ++j) {
                const int grow = bm + wr * 64 + mi * 16 + g * 4 + j;
                float v = acc[mi][ni][j];
                if (QSCALE && gcol < DIM) v *= QSCALE_LOG2E;
                if (WITH_BIAS)
                    ((float*)Cp)[(size_t)grow * N + gcol] = v + bias[gcol];
                else
                    ((unsigned short*)Cp)[(size_t)grow * N + gcol] = f2bf(v);
            }
        }
}

// ---------------------------------------------------------------------------
// MFMA flash attention, SWAPPED-operand form, exp2-domain softmax.
// Q pre-scaled by 0.125*log2e in gemm1 -> sacc is the exp2 exponent.
// Block = 256 thr (4 waves) = 128 q-rows of one (b,h). K-tiles of 64 keys.
//
// mfma(K,Q) -> C[key][q]: lane holds 16 S-values of ONE q -> softmax is
// register-local + 2 shfl. V^T stored key-permuted so each lane's P values
// form its PV B-fragment directly (no LDS round-trip for P).
//
// l-trick: V^T row 64 = ones (bf16), rows 65..79 = 0. The dt=4 PV MFMA then
// accumulates l = sum(P) in oacc[mi][4][0] (lane g=0): k-reduction replaces
// the 32 adds + 4 shfl per tile, and defer-max rescale covers l for free.
// Defer-max (T13, THR=8): skip O-rescale while tile max is within 8 of the
// running max (P bounded by 2^8; exact online-softmax identity).
// ---------------------------------------------------------------------------
__global__ __launch_bounds__(256, 4)
void attn_kernel(const unsigned short* __restrict__ qkv,
                 unsigned short* __restrict__ att)
{
    __shared__ alignas(16) unsigned short Ks[64][64];   // linear (gload_lds dest)
    __shared__ alignas(16) unsigned short Vt[80][80];   // [d][pos]; rows 64..79 const

    const int tid  = threadIdx.x;
    const int lane = tid & 63;
    const int w    = tid >> 6;
    const int b  = blockIdx.z, h = blockIdx.y;
    const int q0 = blockIdx.x * 128;
    const size_t base = (size_t)b * SEQ * QKV_N + (size_t)h * HDIM;

    const int r16 = lane & 15;
    const int g   = lane >> 4;
    const int f7  = r16 & 7;

    // one-time: ones-row (d=64) and zero rows (65..79) of Vt
    if (tid < 80) Vt[64][tid] = 0x3F80;                 // bf16(1.0)
    for (int idx = tid; idx < 15 * 80; idx += 256)
        Vt[65 + idx / 80][idx % 80] = 0;

    // Q fragments (B operand): col=q=r16, elements d = g*8+j (+32)
    short8 qf[2][2];
    #pragma unroll
    for (int mi = 0; mi < 2; ++mi) {
        const unsigned short* qrow =
            qkv + base + (size_t)(q0 + w * 32 + mi * 16 + r16) * QKV_N;
        qf[mi][0] = *(const short8*)(qrow + g * 8);
        qf[mi][1] = *(const short8*)(qrow + 32 + g * 8);
    }

    f32x4 oacc[2][5] = {};          // [mi][dt]: col q=r16, row d=dt*16+g*4+j; dt=4 -> l
    float m_r[2] = { -3e38f, -3e38f };

    // K staging: chunk c covers keys c*8..c*8+7; pre-swizzled source group
    const int krow  = lane >> 3;
    const int kGsrc = (lane & 7) ^ (krow & 7);

    // V staging: lane = key; permuted dest column pos(lane)
    const int k5 = lane & 31, khi = lane >> 5;
    const int vpos = ((k5 < 16) ? ((k5 >> 2) * 8 + (k5 & 3))
                                : (((k5 - 16) >> 2) * 8 + 4 + ((k5 - 16) & 3)))
                     + khi * 32;

    for (int kt = 0; kt < SEQ; kt += 64) {
        __syncthreads();   // prev tile fully consumed
        #pragma unroll
        for (int c = 0; c < 2; ++c) {
            const int chunk = w * 2 + c;
            const unsigned short* gsrc =
                qkv + base + (size_t)(kt + chunk * 8 + krow) * QKV_N + DIM + kGsrc * 8;
            gload16(gsrc, &Ks[chunk * 8][0]);
        }
        {   // stage V transposed+permuted: wave w covers d [w*16,+16)
            const unsigned short* vsrc =
                qkv + base + (size_t)(kt + lane) * QKV_N + 2 * DIM + w * 16;
            short8 v0 = *(const short8*)(vsrc);
            short8 v1 = *(const short8*)(vsrc + 8);
            #pragma unroll
            for (int i = 0; i < 8; ++i) {
                Vt[w * 16 + i][vpos]     = (unsigned short)v0[i];
                Vt[w * 16 + 8 + i][vpos] = (unsigned short)v1[i];
            }
        }
        __syncthreads();

        // --- S^T = K Q^T : C[key][q]  (exp2 domain)
        f32x4 sacc[2][4] = {};
        __builtin_amdgcn_s_setprio(1);
        #pragma unroll
        for (int jt = 0; jt < 4; ++jt) {
            const int row = jt * 16 + r16;
            short8 kf0 = *(const short8*)&Ks[row][(g ^ f7) * 8];
            short8 kf1 = *(const short8*)&Ks[row][((4 + g) ^ f7) * 8];
            sacc[0][jt] = __builtin_amdgcn_mfma_f32_16x16x32_bf16(kf0, qf[0][0], sacc[0][jt], 0, 0, 0);
            sacc[0][jt] = __builtin_amdgcn_mfma_f32_16x16x32_bf16(kf1, qf[0][1], sacc[0][jt], 0, 0, 0);
            sacc[1][jt] = __builtin_amdgcn_mfma_f32_16x16x32_bf16(kf0, qf[1][0], sacc[1][jt], 0, 0, 0);
            sacc[1][jt] = __builtin_amdgcn_mfma_f32_16x16x32_bf16(kf1, qf[1][1], sacc[1][jt], 0, 0, 0);
        }
        __builtin_amdgcn_s_setprio(0);

        // --- softmax (register-local rows, exp2 domain) + lane-local P frags
        short8 pb[2][2];
        #pragma unroll
        for (int mi = 0; mi < 2; ++mi) {
            // max tree in explicit triples (v_max3_f32 fusion)
            const float a0 = fmaxf(fmaxf(sacc[mi][0][0], sacc[mi][0][1]), sacc[mi][0][2]);
            const float a1 = fmaxf(fmaxf(sacc[mi][0][3], sacc[mi][1][0]), sacc[mi][1][1]);
            const float a2 = fmaxf(fmaxf(sacc[mi][1][2], sacc[mi][1][3]), sacc[mi][2][0]);
            const float a3 = fmaxf(fmaxf(sacc[mi][2][1], sacc[mi][2][2]), sacc[mi][2][3]);
            const float a4 = fmaxf(fmaxf(sacc[mi][3][0], sacc[mi][3][1]), sacc[mi][3][2]);
            float tm = fmaxf(fmaxf(fmaxf(a0, a1), a2),
                             fmaxf(fmaxf(a3, a4), sacc[mi][3][3]));
            tm = fmaxf(tm, __shfl_xor(tm, 16));
            tm = fmaxf(tm, __shfl_xor(tm, 32));

            float nm = m_r[mi];
            if (!__all(tm <= m_r[mi] + 8.f)) {       // T13 defer-max, THR=8
                nm = fmaxf(m_r[mi], tm);
                const float f = exp2_fast(m_r[mi] - nm);
                m_r[mi] = nm;
                #pragma unroll
                for (int dt = 0; dt < 5; ++dt)       // includes the l-row
                    #pragma unroll
                    for (int jr = 0; jr < 4; ++jr)
                        oacc[mi][dt][jr] *= f;
            }

            unsigned pw[8];
            #pragma unroll
            for (int jt = 0; jt < 4; ++jt) {
                const float p0 = exp2_fast(sacc[mi][jt][0] - nm);
                const float p1 = exp2_fast(sacc[mi][jt][1] - nm);
                const float p2 = exp2_fast(sacc[mi][jt][2] - nm);
                const float p3 = exp2_fast(sacc[mi][jt][3] - nm);
                pw[jt * 2]     = cvt_pk_bf16(p0, p1);
                pw[jt * 2 + 1] = cvt_pk_bf16(p2, p3);
            }

            union { unsigned u[4]; short8 s; } c0, c1;
            c0.u[0] = pw[0]; c0.u[1] = pw[1]; c0.u[2] = pw[2]; c0.u[3] = pw[3];
            c1.u[0] = pw[4]; c1.u[1] = pw[5]; c1.u[2] = pw[6]; c1.u[3] = pw[7];
            pb[mi][0] = c0.s;   // keys (perm. positions) 0..31
            pb[mi][1] = c1.s;   // keys 32..63
        }

        // --- O^T += V^T P^T (dt=4 accumulates l via the ones-row)
        __builtin_amdgcn_s_setprio(1);
        #pragma unroll
        for (int dt = 0; dt < 5; ++dt) {
            short8 vf0 = *(const short8*)&Vt[dt * 16 + r16][g * 8];
            short8 vf1 = *(const short8*)&Vt[dt * 16 + r16][32 + g * 8];
            #pragma unroll
            for (int mi = 0; mi < 2; ++mi) {
                oacc[mi][dt] = __builtin_amdgcn_mfma_f32_16x16x32_bf16(vf0, pb[mi][0], oacc[mi][dt], 0, 0, 0);
                oacc[mi][dt] = __builtin_amdgcn_mfma_f32_16x16x32_bf16(vf1, pb[mi][1], oacc[mi][dt], 0, 0, 0);
            }
        }
        __builtin_amdgcn_s_setprio(0);
    }

    // epilogue: O^T[d][q] -> att[q][h*64+d]; l = oacc[mi][4][0] @ lane q (g=0)
    #pragma unroll
    for (int mi = 0; mi < 2; ++mi) {
        const float inv = 1.f / __shfl(oacc[mi][4][0], r16);
        const int q = q0 + w * 32 + mi * 16 + r16;
        unsigned short* dst = att + (size_t)(b * SEQ + q) * DIM + h * HDIM;
        #pragma unroll
        for (int dt = 0; dt < 4; ++dt)
            #pragma unroll
            for (int jr = 0; jr < 4; ++jr)
                dst[dt * 16 + g * 4 + jr] = f2bf(oacc[mi][dt][jr] * inv);
    }
}

// ---------------------------------------------------------------------------
extern "C" void kernel_launch(void* const* d_in, const int* in_sizes, int n_in,
                              void* d_out, int out_size, void* d_ws, size_t ws_size,
                              hipStream_t stream)
{
    const float* x     = (const float*)d_in[0];
    const float* w_qkv = (const float*)d_in[1];
    const float* w_out = (const float*)d_in[2];
    const float* b_out = (const float*)d_in[3];
    float* out = (float*)d_out;

    unsigned short* qkv   = (unsigned short*)d_ws;      // [8192][3072]
    unsigned short* xb    = qkv + 25165824;             // [8192][1024] (aliased w/ att)
    unsigned short* att   = xb;
    unsigned short* wqkvT = qkv + 33554432;             // [3072][1024]
    unsigned short* woutT = qkv + 36700160;             // [1024][1024]

    conv_kernel<<<dim3(ROWS * DIM / 4 / 256), 256, 0, stream>>>(x, xb, ROWS * DIM / 4);
    convT_kernel<<<dim3(QKV_N / 32, DIM / 32), 256, 0, stream>>>(w_qkv, wqkvT, DIM, QKV_N);
    convT_kernel<<<dim3(DIM / 32, DIM / 32), 256, 0, stream>>>(w_out, woutT, DIM, DIM);

    gemm_kernel<false, true><<<dim3(QKV_N / 128, ROWS / 128), 256, 0, stream>>>(
        xb, wqkvT, nullptr, qkv, ROWS, QKV_N, DIM);

    attn_kernel<<<dim3(SEQ / 128, NHEADS, BATCH), 256, 0, stream>>>(qkv, att);

    gemm_kernel<true, false><<<dim3(DIM / 128, ROWS / 128), 256, 0, stream>>>(
        att, woutT, b_out, out, ROWS, DIM, DIM);
}